// Round 1
// baseline (170.894 us; speedup 1.0000x reference)
//
#include <hip/hip_runtime.h>
#include <hip/hip_bf16.h>

// Problem constants (from reference): B=64, N=1024, D=8, S=16
#define BB 64
#define NN 1024
#define DD 8
#define SS 16
#define DS 128           // D*S
#define LDK 72           // padded LDS k-stride in ushorts (144 B = 9*16B, 16B-aligned rows, conflict-free)

typedef __attribute__((ext_vector_type(8))) short short8;
typedef __attribute__((ext_vector_type(4))) float floatx4;

static __device__ __forceinline__ unsigned short f2bf(float f) {
    unsigned int u = __float_as_uint(f);
    unsigned int r = (u + 0x7FFFu + ((u >> 16) & 1u)) >> 16;   // RNE
    return (unsigned short)r;
}

// ---------------- Kernel 1: convert matriz_conexao (values are exactly 0.0/1.0) to bf16 ----------------
__global__ void convert_M(const float* __restrict__ M, unsigned short* __restrict__ Mb) {
    int i = (blockIdx.x * 256 + threadIdx.x) * 4;
    float4 v = *(const float4*)(M + i);
    unsigned int p0 = (unsigned int)f2bf(v.x) | ((unsigned int)f2bf(v.y) << 16);
    unsigned int p1 = (unsigned int)f2bf(v.z) | ((unsigned int)f2bf(v.w) << 16);
    *(uint2*)(Mb + i) = make_uint2(p0, p1);
}

// ---------------- Kernel 2: x[b][i][ds] fp32  ->  xT[b][ds][i] bf16 (k-contiguous for GEMM B operand) ----
__global__ void transpose_x(const float* __restrict__ x, unsigned short* __restrict__ xT) {
    __shared__ float tile[64 * 68];          // 64x64 fp32 tile, stride 68 (16B-aligned rows)
    const int t  = threadIdx.x;
    const int b  = blockIdx.z;
    const int i0 = blockIdx.x * 64;
    const int c0 = blockIdx.y * 64;
    const float* xb = x + (size_t)b * (NN * DS);

#pragma unroll
    for (int jj = 0; jj < 4; ++jj) {
        int il = (t >> 4) + jj * 16;         // 0..63
        int cl = (t & 15) * 4;               // 0..60
        float4 v = *(const float4*)(xb + (size_t)(i0 + il) * DS + c0 + cl);
        *(float4*)(tile + il * 68 + cl) = v;
    }
    __syncthreads();
    // write 64 bf16 rows (row = ds), each thread writes 16 contiguous i's (32 B)
    int cr = t >> 2;                         // 0..63 : local ds row
    int iq = (t & 3) * 16;                   // i sub-offset
    unsigned int p[8];
#pragma unroll
    for (int j = 0; j < 8; ++j) {
        unsigned short lo = f2bf(tile[(iq + 2 * j + 0) * 68 + cr]);
        unsigned short hi = f2bf(tile[(iq + 2 * j + 1) * 68 + cr]);
        p[j] = (unsigned int)lo | ((unsigned int)hi << 16);
    }
    unsigned short* dst = xT + (size_t)b * (NN * DS) + (size_t)(c0 + cr) * NN + i0 + iq;
    *(uint4*)(dst + 0) = make_uint4(p[0], p[1], p[2], p[3]);
    *(uint4*)(dst + 8) = make_uint4(p[4], p[5], p[6], p[7]);
}

// ---------------- Kernel 3: fused GEMM (xm = M @ x_b) + dendrite tanh + soma sigmoid ----------------
// grid = (B, N/128); block = 256 (4 waves). Tile: 128 o x 128 ds, K = 1024 over i.
__global__ __launch_bounds__(256, 2) void gemm_fused(
    const unsigned short* __restrict__ Mb,   // [N][N] bf16, row o, col i (k-contiguous)
    const unsigned short* __restrict__ xT,   // [B][DS][N] bf16, row ds, col i (k-contiguous)
    const float* __restrict__ w_syn,         // [N][D][S]
    const float* __restrict__ b_dend,        // [N][D]
    const float* __restrict__ w_dend,        // [N][D]
    const float* __restrict__ b_soma,        // [N]
    float* __restrict__ out)                 // [B][N]
{
    __shared__ __align__(16) char smem[128 * 129 * 4];    // 66048 B: staging (36864 B) then C-tile
    unsigned short* As = (unsigned short*)smem;           // [128][LDK]  (o rows)
    unsigned short* Bs = As + 128 * LDK;                  // [128][LDK]  (ds rows)
    float* Cs = (float*)smem;                             // [128][129]  (epilogue reuse)

    const int t      = threadIdx.x;
    const int b      = blockIdx.x;            // b fastest -> same-b blocks share an XCD's L2
    const int o_base = blockIdx.y * 128;

    const unsigned short* Ag = Mb + (size_t)o_base * NN;
    const unsigned short* Bg = xT + (size_t)b * (NN * DS);

    const int lane = t & 63;
    const int w    = t >> 6;
    const int wr   = (w >> 1) * 64;           // wave row offset (o)
    const int wc   = (w & 1) * 64;            // wave col offset (ds)
    const int lm   = lane & 15;
    const int kq   = lane >> 4;               // 0..3

    floatx4 acc[4][4] = {};

    for (int kt = 0; kt < 16; ++kt) {
        const int k0 = kt * 64;
        uint4 av[4], bv[4];
#pragma unroll
        for (int j = 0; j < 4; ++j) {
            int G = t + 256 * j;              // granule id 0..1023
            int row = G >> 3, cg = G & 7;     // row 0..127, 16B-granule 0..7
            av[j] = *(const uint4*)(Ag + (size_t)row * NN + k0 + cg * 8);
            bv[j] = *(const uint4*)(Bg + (size_t)row * NN + k0 + cg * 8);
        }
        __syncthreads();                       // previous tile's frag reads done
#pragma unroll
        for (int j = 0; j < 4; ++j) {
            int G = t + 256 * j;
            int row = G >> 3, cg = G & 7;
            *(uint4*)(As + row * LDK + cg * 8) = av[j];
            *(uint4*)(Bs + row * LDK + cg * 8) = bv[j];
        }
        __syncthreads();
#pragma unroll
        for (int ks = 0; ks < 2; ++ks) {
            short8 af[4], bf[4];
#pragma unroll
            for (int r = 0; r < 4; ++r)
                af[r] = *(const short8*)(As + (wr + r * 16 + lm) * LDK + ks * 32 + kq * 8);
#pragma unroll
            for (int c = 0; c < 4; ++c)
                bf[c] = *(const short8*)(Bs + (wc + c * 16 + lm) * LDK + ks * 32 + kq * 8);
#pragma unroll
            for (int r = 0; r < 4; ++r)
#pragma unroll
                for (int c = 0; c < 4; ++c)
                    acc[r][c] = __builtin_amdgcn_mfma_f32_16x16x32_bf16(af[r], bf[c], acc[r][c], 0, 0, 0);
        }
    }

    __syncthreads();                           // all LDS staging reads done before reuse as Cs
    // C/D layout (verified m89/m91): col = lane&15, row = (lane>>4)*4 + reg
#pragma unroll
    for (int r = 0; r < 4; ++r) {
#pragma unroll
        for (int c = 0; c < 4; ++c) {
            int col  = wc + c * 16 + lm;
            int row0 = wr + r * 16 + kq * 4;
            Cs[(row0 + 0) * 129 + col] = acc[r][c][0];
            Cs[(row0 + 1) * 129 + col] = acc[r][c][1];
            Cs[(row0 + 2) * 129 + col] = acc[r][c][2];
            Cs[(row0 + 3) * 129 + col] = acc[r][c][3];
        }
    }
    __syncthreads();

    // Epilogue: 2 threads per o (4 dendrites each), fp32 throughout
    {
        const int o_l = t >> 1;
        const int dh  = (t & 1) * 4;
        const int o   = o_base + o_l;
        float part = 0.f;
#pragma unroll
        for (int dd = 0; dd < 4; ++dd) {
            int d = dh + dd;
            float pre = b_dend[o * DD + d];
            const float* wsn = w_syn + (size_t)o * DS + d * SS;
            const float* cr  = Cs + o_l * 129 + d * SS;
#pragma unroll
            for (int s = 0; s < SS; ++s) pre += cr[s] * wsn[s];
            part += tanhf(pre) * w_dend[o * DD + d];
        }
        part += __shfl_xor(part, 1);
        if ((t & 1) == 0) {
            float soma = part + b_soma[o];
            out[(size_t)b * NN + o] = 1.f / (1.f + __expf(-soma));
        }
    }
}

extern "C" void kernel_launch(void* const* d_in, const int* in_sizes, int n_in,
                              void* d_out, int out_size, void* d_ws, size_t ws_size,
                              hipStream_t stream) {
    const float* x      = (const float*)d_in[0];   // [B,N,D,S]
    const float* M      = (const float*)d_in[1];   // [N,N]
    const float* w_syn  = (const float*)d_in[2];   // [N,D,S]
    const float* b_dend = (const float*)d_in[3];   // [N,D]
    const float* w_dend = (const float*)d_in[4];   // [N,D]
    const float* b_soma = (const float*)d_in[5];   // [N]
    float* out = (float*)d_out;

    unsigned short* xT = (unsigned short*)d_ws;                 // [B][DS][N] bf16 : 16 MiB
    unsigned short* Mb = xT + (size_t)BB * NN * DS;             // [N][N]   bf16 :  2 MiB

    convert_M  <<<dim3(NN * NN / (256 * 4)), 256, 0, stream>>>(M, Mb);
    transpose_x<<<dim3(NN / 64, DS / 64, BB), 256, 0, stream>>>(x, xT);
    gemm_fused <<<dim3(BB, NN / 128), 256, 0, stream>>>(Mb, xT, w_syn, b_dend, w_dend, b_soma, out);
}

// Round 2
// 110.661 us; speedup vs baseline: 1.5443x; 1.5443x over previous
//
#include <hip/hip_runtime.h>
#include <hip/hip_bf16.h>

// Problem constants (from reference): B=64, N=1024, D=8, S=16
#define BB 64
#define NN 1024
#define DD 8
#define SS 16
#define DS 128           // D*S

typedef __attribute__((ext_vector_type(8))) short short8;
typedef __attribute__((ext_vector_type(4))) float floatx4;

typedef __attribute__((address_space(1))) const unsigned int glds_src;
typedef __attribute__((address_space(3))) unsigned int glds_dst;

static __device__ __forceinline__ unsigned short f2bf(float f) {
    unsigned int u = __float_as_uint(f);
    unsigned int r = (u + 0x7FFFu + ((u >> 16) & 1u)) >> 16;   // RNE
    return (unsigned short)r;
}

// ---------------- Kernel 1: convert matriz_conexao (values exactly 0.0/1.0) to bf16 ----------------
__global__ void convert_M(const float* __restrict__ M, unsigned short* __restrict__ Mb) {
    int i = (blockIdx.x * 256 + threadIdx.x) * 4;
    float4 v = *(const float4*)(M + i);
    unsigned int p0 = (unsigned int)f2bf(v.x) | ((unsigned int)f2bf(v.y) << 16);
    unsigned int p1 = (unsigned int)f2bf(v.z) | ((unsigned int)f2bf(v.w) << 16);
    *(uint2*)(Mb + i) = make_uint2(p0, p1);
}

// ---------------- Kernel 2: x[b][i][ds] fp32  ->  xT[b][ds][i] bf16 (k-contiguous for GEMM B operand) ----
__global__ void transpose_x(const float* __restrict__ x, unsigned short* __restrict__ xT) {
    __shared__ float tile[64 * 68];          // 64x64 fp32 tile, stride 68 (16B-aligned rows)
    const int t  = threadIdx.x;
    const int b  = blockIdx.z;
    const int i0 = blockIdx.x * 64;
    const int c0 = blockIdx.y * 64;
    const float* xb = x + (size_t)b * (NN * DS);

#pragma unroll
    for (int jj = 0; jj < 4; ++jj) {
        int il = (t >> 4) + jj * 16;         // 0..63
        int cl = (t & 15) * 4;               // 0..60
        float4 v = *(const float4*)(xb + (size_t)(i0 + il) * DS + c0 + cl);
        *(float4*)(tile + il * 68 + cl) = v;
    }
    __syncthreads();
    // write 64 bf16 rows (row = ds), each thread writes 16 contiguous i's (32 B)
    int cr  = t >> 2;                        // 0..63 : local ds row
    int iq  = (t & 3) * 16;                  // i sub-offset
    int rot = (t & 3) * 2;                   // j-rotation: breaks the 4-way bank conflict
    unsigned int p[8];
#pragma unroll
    for (int j = 0; j < 8; ++j) {
        int jp = (j + rot) & 7;
        unsigned short lo = f2bf(tile[(iq + 2 * jp + 0) * 68 + cr]);
        unsigned short hi = f2bf(tile[(iq + 2 * jp + 1) * 68 + cr]);
        p[jp] = (unsigned int)lo | ((unsigned int)hi << 16);
    }
    unsigned short* dst = xT + (size_t)b * (NN * DS) + (size_t)(c0 + cr) * NN + i0 + iq;
    *(uint4*)(dst + 0) = make_uint4(p[0], p[1], p[2], p[3]);
    *(uint4*)(dst + 8) = make_uint4(p[4], p[5], p[6], p[7]);
}

// ---------------- Kernel 3: fused GEMM (xm = M @ x_b) + dendrite tanh + soma sigmoid ----------------
// grid = (B, N/128); block = 256 (4 waves). Tile: 128 o x 128 ds, K = 1024 over i.
// Staging via global_load_lds (width=16): no VGPR round-trip, no spill.
// LDS tiles are unpadded [128 rows][64 ushorts], XOR-swizzled: global granule g of row r
// lives at LDS granule g ^ (r&7). Both staging and ds_read_b128 frag reads hit the
// wave64 bank minimum (verified: 8 accesses/bank, uniform).
__global__ __launch_bounds__(256, 2) void gemm_fused(
    const unsigned short* __restrict__ Mb,   // [N][N] bf16, row o, col i (k-contiguous)
    const unsigned short* __restrict__ xT,   // [B][DS][N] bf16, row ds, col i (k-contiguous)
    const float* __restrict__ w_syn,         // [N][D][S]
    const float* __restrict__ b_dend,        // [N][D]
    const float* __restrict__ w_dend,        // [N][D]
    const float* __restrict__ b_soma,        // [N]
    float* __restrict__ out)                 // [B][N]
{
    __shared__ __align__(16) char smem[128 * 129 * 4];    // 66048 B: staging (32 KB) then C-tile
    unsigned short* As = (unsigned short*)smem;           // [128][64]  (o rows)    16 KB
    unsigned short* Bs = As + 128 * 64;                   // [128][64]  (ds rows)   16 KB
    float* Cs = (float*)smem;                             // [128][129] (epilogue reuse)

    const int t      = threadIdx.x;
    const int b      = blockIdx.x;            // b fastest -> same-b blocks share an XCD's L2
    const int o_base = blockIdx.y * 128;

    const char* AgB = (const char*)(Mb + (size_t)o_base * NN);
    const char* BgB = (const char*)(xT + (size_t)b * (NN * DS));

    const int lane = t & 63;
    const int w    = t >> 6;
    const int wr   = (w >> 1) * 64;           // wave row offset (o)
    const int wc   = (w & 1) * 64;            // wave col offset (ds)
    const int lm   = lane & 15;
    const int kq   = lane >> 4;               // 0..3

    // per-lane source offsets for the 4 staging DMAs of this wave (shared by A and B:
    // both have row stride NN*2 bytes). Row = (w*4+j)*8 + (lane>>3); source granule
    // is XOR-swizzled so LDS granule (lane&7) of that row holds global granule
    // (lane&7)^(row&7).
    const int lr = lane >> 3;                              // 0..7
    const int lg = (lane & 7) ^ lr;                        // swizzled source granule
    int off[4];
#pragma unroll
    for (int j = 0; j < 4; ++j)
        off[j] = ((w * 4 + j) * 8 + lr) * (NN * 2) + lg * 16;

    floatx4 acc[4][4] = {};

    for (int kt = 0; kt < 16; ++kt) {
        const int kb = kt * 128;               // byte offset along k within a row
        __syncthreads();                       // previous tile's frag reads done
#pragma unroll
        for (int j = 0; j < 4; ++j) {
            __builtin_amdgcn_global_load_lds(
                (glds_src*)(AgB + off[j] + kb),
                (glds_dst*)((char*)As + (w * 4 + j) * 1024), 16, 0, 0);
            __builtin_amdgcn_global_load_lds(
                (glds_src*)(BgB + off[j] + kb),
                (glds_dst*)((char*)Bs + (w * 4 + j) * 1024), 16, 0, 0);
        }
        __syncthreads();                       // drains vmcnt(0): tiles staged
#pragma unroll
        for (int ks = 0; ks < 2; ++ks) {
            short8 af[4], bf[4];
            const int g = (((ks * 4 + kq) ^ (lm & 7)) * 8); // swizzled ushort offset in row
#pragma unroll
            for (int r = 0; r < 4; ++r)
                af[r] = *(const short8*)(As + (wr + r * 16 + lm) * 64 + g);
#pragma unroll
            for (int c = 0; c < 4; ++c)
                bf[c] = *(const short8*)(Bs + (wc + c * 16 + lm) * 64 + g);
#pragma unroll
            for (int r = 0; r < 4; ++r)
#pragma unroll
                for (int c = 0; c < 4; ++c)
                    acc[r][c] = __builtin_amdgcn_mfma_f32_16x16x32_bf16(af[r], bf[c], acc[r][c], 0, 0, 0);
        }
    }

    __syncthreads();                           // all LDS tile reads done before reuse as Cs
    // C/D layout (verified m89/m91): col = lane&15, row = (lane>>4)*4 + reg
#pragma unroll
    for (int r = 0; r < 4; ++r) {
#pragma unroll
        for (int c = 0; c < 4; ++c) {
            int col  = wc + c * 16 + lm;
            int row0 = wr + r * 16 + kq * 4;
            Cs[(row0 + 0) * 129 + col] = acc[r][c][0];
            Cs[(row0 + 1) * 129 + col] = acc[r][c][1];
            Cs[(row0 + 2) * 129 + col] = acc[r][c][2];
            Cs[(row0 + 3) * 129 + col] = acc[r][c][3];
        }
    }
    __syncthreads();

    // Epilogue: 2 threads per o (4 dendrites each), fp32 throughout
    {
        const int o_l = t >> 1;
        const int dh  = (t & 1) * 4;
        const int o   = o_base + o_l;
        float part = 0.f;
#pragma unroll
        for (int dd = 0; dd < 4; ++dd) {
            int d = dh + dd;
            float pre = b_dend[o * DD + d];
            const float* wsn = w_syn + (size_t)o * DS + d * SS;
            const float* cr  = Cs + o_l * 129 + d * SS;
#pragma unroll
            for (int s = 0; s < SS; ++s) pre += cr[s] * wsn[s];
            part += tanhf(pre) * w_dend[o * DD + d];
        }
        part += __shfl_xor(part, 1);
        if ((t & 1) == 0) {
            float soma = part + b_soma[o];
            out[(size_t)b * NN + o] = 1.f / (1.f + __expf(-soma));
        }
    }
}

extern "C" void kernel_launch(void* const* d_in, const int* in_sizes, int n_in,
                              void* d_out, int out_size, void* d_ws, size_t ws_size,
                              hipStream_t stream) {
    const float* x      = (const float*)d_in[0];   // [B,N,D,S]
    const float* M      = (const float*)d_in[1];   // [N,N]
    const float* w_syn  = (const float*)d_in[2];   // [N,D,S]
    const float* b_dend = (const float*)d_in[3];   // [N,D]
    const float* w_dend = (const float*)d_in[4];   // [N,D]
    const float* b_soma = (const float*)d_in[5];   // [N]
    float* out = (float*)d_out;

    unsigned short* xT = (unsigned short*)d_ws;                 // [B][DS][N] bf16 : 16 MiB
    unsigned short* Mb = xT + (size_t)BB * NN * DS;             // [N][N]   bf16 :  2 MiB

    convert_M  <<<dim3(NN * NN / (256 * 4)), 256, 0, stream>>>(M, Mb);
    transpose_x<<<dim3(NN / 64, DS / 64, BB), 256, 0, stream>>>(x, xT);
    gemm_fused <<<dim3(BB, NN / 128), 256, 0, stream>>>(Mb, xT, w_syn, b_dend, w_dend, b_soma, out);
}